// Round 20
// baseline (115.952 us; speedup 1.0000x reference)
//
#include <hip/hip_runtime.h>
#include <hip/hip_bf16.h>

typedef short short8 __attribute__((ext_vector_type(8)));
typedef short short4_t __attribute__((ext_vector_type(4)));
typedef float floatx4 __attribute__((ext_vector_type(4)));
typedef unsigned short ushort_t;
typedef unsigned int uint32;

#define H 320
#define W 320
#define CG 16
#define NCH 64
#define HW (H * W)
#define CGP 20       // ushorts per LDS col (40B): conflict-free frag reads (measured 0)
#define HALFW 160

__device__ __forceinline__ ushort_t f2bf(float f) {
  unsigned u = __float_as_uint(f);
  return (ushort_t)((u + 0x7FFFu + ((u >> 16) & 1u)) >> 16);  // RNE (weights only)
}

// LDS-only barrier: does NOT drain vmcnt -> global loads/stores stay in flight.
__device__ __forceinline__ void barrier_lgkm() {
  asm volatile("s_waitcnt lgkmcnt(0)" ::: "memory");
  __builtin_amdgcn_s_barrier();
}

// r20 = r17 byte-for-byte with ONE flip: plain dwordx4 store instead of
// nontemporal. A/B under the balanced XCD map (the pre-swizzle A/B r13/r15
// is stale: the map changed L2 behavior, FETCH 133->112 MB). Plain saves
// 32 MB HBM writes (~9 us at the observed 3.6 TB/s service rate) if nt's
// old +13 us was pollution-latency (now covered by the swizzle).
template<int G>
__device__ __forceinline__ void conv_group(
    const float* __restrict__ x, const float* __restrict__ wgt,
    const float* __restrict__ bias, float* __restrict__ out,
    ushort_t* lds, int b, int bx) {
  constexpr int DIL   = (G == 0) ? 1 : (G == 1) ? 6 : (G == 2) ? 12 : 18;
  constexpr int KOFF  = DIL & 1;
  constexpr int SHIFT = DIL + KOFF;              // lds col c <-> global col wb + c - SHIFT
  constexpr int WH    = (HALFW + 2 * DIL + KOFF + 1) & ~1;  // 164/172/184/196
  constexpr int NP    = (WH + 63) / 64;          // 3/3/3/4
  constexpr int RPW   = (H + DIL - 1) / DIL;
  constexpr int Q     = (RPW + 3) / 4;           // 80/14/7/5 tasks per walk
  constexpr int CPW   = (G == 0) ? 12 : (G == 1) ? 2 : 1;
  constexpr int L     = (Q + CPW - 1) / CPW;     // 7/7/7/5 tasks per chunk

  const int tid = threadIdx.x;
  ushort_t* tile = lds;                          // [6][WH][CGP]
  ushort_t* swt  = lds + 6 * WH * CGP;           // [5][4][16][8] w-frag table
  uint32* swt32  = (uint32*)swt;

  // ---- weight fragment table (once per block) ----
#pragma unroll
  for (int k = 0; k < 5; ++k) {
    const int s = tid + k * 256;
    const int jp = s & 3, oc = (s >> 2) & 15, zz = (s >> 6) & 3, t = s >> 8;
    const int tp = 2 * t + (zz >> 1);
    uint32 pk = 0;
    if (tp < 9) {
      const float* wp = wgt + ((size_t)(G * CG + oc) * CG + (zz & 1) * 8 + 2 * jp) * 9 + tp;
      pk = (uint32)f2bf(wp[0]) | ((uint32)f2bf(wp[9]) << 16);
    }
    swt32[s] = pk;
  }
  __syncthreads();

  const int lane = tid & 63;
  const int wv   = tid >> 6;
  const int z = lane >> 4, icq = z & 1, pxl = lane & 15;
  short8 aw[5];
#pragma unroll
  for (int t = 0; t < 5; ++t) aw[t] = *(const short8*)&swt[((t * 4 + z) * 16 + pxl) * 8];
  const float bb = bias[G * CG + pxl];           // oc = lane&15 in swapped layout

  // ---- decode group-local bx -> (wb, r, chunk); b passed in (= XCD) ----
  const int chunk = bx % CPW;
  const int t1 = bx / CPW;
  const int r  = t1 % DIL;
  const int wb = (t1 / DIL) * HALFW;             // t1/DIL in {0,1}
  const int q0 = chunk * L;
  const int qend = (q0 + L < Q) ? q0 + L : Q;

  // ---- staging constants: thread = (col = lane, ch-quad = wv) ----
  bool zm[NP]; bool inb[NP]; int gofs[NP];
#pragma unroll
  for (int p = 0; p < NP; ++p) {
    const int c = 64 * p + lane;
    inb[p] = (c < WH);
    const int gc = wb + c - SHIFT;
    zm[p] = inb[p] & (gc >= 0) & (gc < W);
    gofs[p] = gc < 0 ? 0 : (gc >= W ? W - 1 : gc);
  }
  const float* chb = x + (size_t)(b * NCH + G * CG + 4 * wv) * HW;

  auto LOADR = [&](int rho, float (&rg)[NP][4]) {
    const int yy = rho * DIL + r;
    const int yyc = yy < 0 ? 0 : (yy >= H ? H - 1 : yy);
    const float* rp = chb + (size_t)yyc * W;
#pragma unroll
    for (int p = 0; p < NP; ++p)
#pragma unroll
      for (int k = 0; k < 4; ++k)
        rg[p][k] = rp[(size_t)k * HW + gofs[p]];   // 256B coalesced per inst
  };

  auto CVTR = [&](int rho, int slot, float (&rg)[NP][4]) {
    const int yy = rho * DIL + r;
    const bool rv = (yy >= 0) & (yy < H);
#pragma unroll
    for (int p = 0; p < NP; ++p) {
      const bool m = rv & zm[p];
      const __hip_bfloat162 h01 = __float22bfloat162_rn(make_float2(rg[p][0], rg[p][1]));
      const __hip_bfloat162 h23 = __float22bfloat162_rn(make_float2(rg[p][2], rg[p][3]));
      uint2 pk;
      pk.x = m ? *(const uint32*)&h01 : 0u;
      pk.y = m ? *(const uint32*)&h23 : 0u;
      if (inb[p]) {
        const int c = 64 * p + lane;
        *(uint2*)&tile[(size_t)(slot * WH + c) * CGP + wv * 4] = pk;  // ds_write_b64
      }
    }
  };

  auto COMPUTE = [&](int q, int m6) {
    const int y = (4 * q + wv) * DIL + r;
    if (y >= H) return;
    const int zh = z >> 1;
    // swapped C/D: lane&15 = oc, regs = px {4z..4z+3}
    float* outb = out + (size_t)(b * NCH + G * CG + pxl) * HW + (size_t)y * W + wb + 4 * z;
    const ushort_t* rowp[5];                 // statically indexed (unrolled t)
#pragma unroll
    for (int t = 0; t < 5; ++t) {
      const int tp = 2 * t + zh;
      const int ky = tp < 9 ? tp / 3 : 0;
      const int kx = tp < 9 ? tp - ky * 3 : 0;
      int s = m6 + wv + ky; s -= (s >= 6) ? 6 : 0;   // slot of row j = wv+ky
      rowp[t] = tile + (size_t)s * (WH * CGP) + (size_t)(pxl + kx * DIL + KOFF) * CGP + icq * 8;
    }
#pragma unroll 2
    for (int ti = 0; ti < HALFW / 16; ++ti) {
      floatx4 acc = {0.f, 0.f, 0.f, 0.f};
#pragma unroll
      for (int t = 0; t < 5; ++t) {
        const ushort_t* pf = rowp[t] + ti * 16 * CGP;
        const short4_t lo = *(const short4_t*)pf;
        const short4_t hi = *(const short4_t*)(pf + 4);
        const short8 bf = {lo[0], lo[1], lo[2], lo[3], hi[0], hi[1], hi[2], hi[3]};
        acc = __builtin_amdgcn_mfma_f32_16x16x32_bf16(bf, aw[t], acc, 0, 0, 0);  // A=x, B=w
      }
      floatx4 st = {acc[0] + bb, acc[1] + bb, acc[2] + bb, acc[3] + bb};
      *(floatx4*)(outb + ti * 16) = st;      // PLAIN dwordx4 (the A/B variable)
    }
  };

  auto wrap6 = [](int v) { return v >= 6 ? v - 6 : v; };
  int m6 = (4 * q0 + 5) % 6;                 // slot of row rho = 4q-1 (ring-6)

  // ---- prologue: stage 6 rows ----
  {
    float ra[NP][4], rb[NP][4];
    LOADR(4 * q0 - 1, ra); LOADR(4 * q0 + 0, rb);
    CVTR(4 * q0 - 1, wrap6(m6 + 0), ra); CVTR(4 * q0 + 0, wrap6(m6 + 1), rb);
    LOADR(4 * q0 + 1, ra); LOADR(4 * q0 + 2, rb);
    CVTR(4 * q0 + 1, wrap6(m6 + 2), ra); CVTR(4 * q0 + 2, wrap6(m6 + 3), rb);
    LOADR(4 * q0 + 3, ra); LOADR(4 * q0 + 4, rb);
    CVTR(4 * q0 + 3, wrap6(m6 + 4), ra); CVTR(4 * q0 + 4, wrap6(m6 + 5), rb);
  }
  barrier_lgkm();

  // ---- task loop: straight-line body; final iteration peeled ----
#pragma unroll 1
  for (int q = q0; q < qend - 1; ++q) {
    float ra[NP][4], rb[NP][4], rc[NP][4], rd[NP][4];
    LOADR(4 * q + 5, ra); LOADR(4 * q + 6, rb);
    LOADR(4 * q + 7, rc); LOADR(4 * q + 8, rd);
    COMPUTE(q, m6);                          // prefetch drains under this
    barrier_lgkm();                          // tile readers done (lgkm only)
    CVTR(4 * q + 5, m6,            ra);
    CVTR(4 * q + 6, wrap6(m6 + 1), rb);
    CVTR(4 * q + 7, wrap6(m6 + 2), rc);
    CVTR(4 * q + 8, wrap6(m6 + 3), rd);
    barrier_lgkm();                          // tile ready for next task
    m6 = wrap6(m6 + 4);
  }
  COMPUTE(qend - 1, m6);                     // epilogue: no staging
}

extern "C" __global__ void __launch_bounds__(256, 3) conv_all(
    const float* __restrict__ x, const float* __restrict__ wgt,
    const float* __restrict__ bias, float* __restrict__ out) {
  extern __shared__ ushort_t lds[];
  // Balanced XCD map: xcd = bid&7 = batch; j = bid>>3 indexes the batch's 108
  // blocks ordered [G3(36) | G2(24) | G1(24) | G0(24)], each [wb][r][chunk].
  const int bid = blockIdx.x;
  const int b = bid & 7;
  const int j = bid >> 3;
  if (j < 36)      conv_group<3>(x, wgt, bias, out, lds, b, j);       // 2*18*1
  else if (j < 60) conv_group<2>(x, wgt, bias, out, lds, b, j - 36);  // 2*12*1
  else if (j < 84) conv_group<1>(x, wgt, bias, out, lds, b, j - 60);  // 2*6*2
  else             conv_group<0>(x, wgt, bias, out, lds, b, j - 84);  // 2*1*12
}

extern "C" void kernel_launch(void* const* d_in, const int* in_sizes, int n_in,
                              void* d_out, int out_size, void* d_ws, size_t ws_size,
                              hipStream_t stream) {
  const float* x    = (const float*)d_in[0];
  const float* wgt  = (const float*)d_in[1];
  const float* bias = (const float*)d_in[2];
  float* out        = (float*)d_out;

  // dynamic LDS (max over groups, G3): 6*196*20*2 + 5120 = 52160 B -> 3 blocks/CU
  const size_t lds_bytes = (size_t)(6 * 196 * CGP + 5 * 4 * 16 * 8) * 2;
  conv_all<<<dim3(864), dim3(256), lds_bytes, stream>>>(x, wgt, bias, out);
}

// Round 21
// 84.760 us; speedup vs baseline: 1.3680x; 1.3680x over previous
//
#include <hip/hip_runtime.h>
#include <hip/hip_bf16.h>

typedef short short8 __attribute__((ext_vector_type(8)));
typedef short short4_t __attribute__((ext_vector_type(4)));
typedef float floatx4 __attribute__((ext_vector_type(4)));
typedef unsigned short ushort_t;
typedef unsigned int uint32;

#define H 320
#define W 320
#define CG 16
#define NCH 64
#define HW (H * W)
#define CGP 20       // ushorts per LDS col (40B): conflict-free frag reads (measured 0)
#define HALFW 160

__device__ __forceinline__ ushort_t f2bf(float f) {
  unsigned u = __float_as_uint(f);
  return (ushort_t)((u + 0x7FFFu + ((u >> 16) & 1u)) >> 16);  // RNE (weights only)
}

// LDS-only barrier: does NOT drain vmcnt -> global loads/stores stay in flight.
__device__ __forceinline__ void barrier_lgkm() {
  asm volatile("s_waitcnt lgkmcnt(0)" ::: "memory");
  __builtin_amdgcn_s_barrier();
}

// r21 = r17 (best: swapped MFMA + nt store + ring-6 + balanced XCD map) with a
// FULL-LINE store epilogue: ds_bpermute register-transpose so each nt
// dwordx4 instruction covers 8 FULL 128-B lines (8 lanes x 16B per oc-row)
// instead of 16 half-lines (4 lanes x 16B per oc). Theory: nt drain is
// rate-capped (dur ~= WRITE/2.4 TB/s across r13-r19); halving transactions
// and killing the 1.16x partial-line inflation attacks that cap directly.
template<int G>
__device__ __forceinline__ void conv_group(
    const float* __restrict__ x, const float* __restrict__ wgt,
    const float* __restrict__ bias, float* __restrict__ out,
    ushort_t* lds, int b, int bx) {
  constexpr int DIL   = (G == 0) ? 1 : (G == 1) ? 6 : (G == 2) ? 12 : 18;
  constexpr int KOFF  = DIL & 1;
  constexpr int SHIFT = DIL + KOFF;              // lds col c <-> global col wb + c - SHIFT
  constexpr int WH    = (HALFW + 2 * DIL + KOFF + 1) & ~1;  // 164/172/184/196
  constexpr int NP    = (WH + 63) / 64;          // 3/3/3/4
  constexpr int RPW   = (H + DIL - 1) / DIL;
  constexpr int Q     = (RPW + 3) / 4;           // 80/14/7/5 tasks per walk
  constexpr int CPW   = (G == 0) ? 12 : (G == 1) ? 2 : 1;
  constexpr int L     = (Q + CPW - 1) / CPW;     // 7/7/7/5 tasks per chunk

  const int tid = threadIdx.x;
  ushort_t* tile = lds;                          // [6][WH][CGP]
  ushort_t* swt  = lds + 6 * WH * CGP;           // [5][4][16][8] w-frag table
  uint32* swt32  = (uint32*)swt;

  // ---- weight fragment table (once per block) ----
#pragma unroll
  for (int k = 0; k < 5; ++k) {
    const int s = tid + k * 256;
    const int jp = s & 3, oc = (s >> 2) & 15, zz = (s >> 6) & 3, t = s >> 8;
    const int tp = 2 * t + (zz >> 1);
    uint32 pk = 0;
    if (tp < 9) {
      const float* wp = wgt + ((size_t)(G * CG + oc) * CG + (zz & 1) * 8 + 2 * jp) * 9 + tp;
      pk = (uint32)f2bf(wp[0]) | ((uint32)f2bf(wp[9]) << 16);
    }
    swt32[s] = pk;
  }
  __syncthreads();

  const int lane = tid & 63;
  const int wv   = tid >> 6;
  const int z = lane >> 4, icq = z & 1, pxl = lane & 15;
  short8 aw[5];
#pragma unroll
  for (int t = 0; t < 5; ++t) aw[t] = *(const short8*)&swt[((t * 4 + z) * 16 + pxl) * 8];
  const float bb = bias[G * CG + pxl];           // oc = lane&15 in acc layout

  // ---- decode group-local bx -> (wb, r, chunk); b passed in (= XCD) ----
  const int chunk = bx % CPW;
  const int t1 = bx / CPW;
  const int r  = t1 % DIL;
  const int wb = (t1 / DIL) * HALFW;             // t1/DIL in {0,1}
  const int q0 = chunk * L;
  const int qend = (q0 + L < Q) ? q0 + L : Q;

  // ---- staging constants: thread = (col = lane, ch-quad = wv) ----
  bool zm[NP]; bool inb[NP]; int gofs[NP];
#pragma unroll
  for (int p = 0; p < NP; ++p) {
    const int c = 64 * p + lane;
    inb[p] = (c < WH);
    const int gc = wb + c - SHIFT;
    zm[p] = inb[p] & (gc >= 0) & (gc < W);
    gofs[p] = gc < 0 ? 0 : (gc >= W ? W - 1 : gc);
  }
  const float* chb = x + (size_t)(b * NCH + G * CG + 4 * wv) * HW;

  auto LOADR = [&](int rho, float (&rg)[NP][4]) {
    const int yy = rho * DIL + r;
    const int yyc = yy < 0 ? 0 : (yy >= H ? H - 1 : yy);
    const float* rp = chb + (size_t)yyc * W;
#pragma unroll
    for (int p = 0; p < NP; ++p)
#pragma unroll
      for (int k = 0; k < 4; ++k)
        rg[p][k] = rp[(size_t)k * HW + gofs[p]];   // 256B coalesced per inst
  };

  auto CVTR = [&](int rho, int slot, float (&rg)[NP][4]) {
    const int yy = rho * DIL + r;
    const bool rv = (yy >= 0) & (yy < H);
#pragma unroll
    for (int p = 0; p < NP; ++p) {
      const bool m = rv & zm[p];
      const __hip_bfloat162 h01 = __float22bfloat162_rn(make_float2(rg[p][0], rg[p][1]));
      const __hip_bfloat162 h23 = __float22bfloat162_rn(make_float2(rg[p][2], rg[p][3]));
      uint2 pk;
      pk.x = m ? *(const uint32*)&h01 : 0u;
      pk.y = m ? *(const uint32*)&h23 : 0u;
      if (inb[p]) {
        const int c = 64 * p + lane;
        *(uint2*)&tile[(size_t)(slot * WH + c) * CGP + wv * 4] = pk;  // ds_write_b64
      }
    }
  };

  auto COMPUTE = [&](int q, int m6) {
    const int y = (4 * q + wv) * DIL + r;
    if (y >= H) return;
    const int zh = z >> 1;
    const ushort_t* rowp[5];                 // statically indexed (unrolled t)
#pragma unroll
    for (int t = 0; t < 5; ++t) {
      const int tp = 2 * t + zh;
      const int ky = tp < 9 ? tp / 3 : 0;
      const int kx = tp < 9 ? tp - ky * 3 : 0;
      int s = m6 + wv + ky; s -= (s >= 6) ? 6 : 0;   // slot of row j = wv+ky
      rowp[t] = tile + (size_t)s * (WH * CGP) + (size_t)(pxl + kx * DIL + KOFF) * CGP + icq * 8;
    }
    // store-transpose constants: lane l stores px (l&7)*4..+3 of oc (l>>3)+8m
    const int qq  = lane & 7;
    const int oc0 = lane >> 3;
    const bool hi = qq >= 4;                 // px quad from a1 (px 16..31)
    const int sl0 = (oc0 + 16 * (qq & 3)) << 2;      // src lane*4, m=0
    const int sl1 = (oc0 + 8 + 16 * (qq & 3)) << 2;  // src lane*4, m=1
    float* outr0 = out + (size_t)(b * NCH + G * CG + oc0) * HW + (size_t)y * W + wb + qq * 4;
    float* outr1 = outr0 + (size_t)8 * HW;
#pragma unroll 1
    for (int tj = 0; tj < HALFW / 32; ++tj) {  // 32-px pairs (128B per oc-row)
      floatx4 a0 = {0.f, 0.f, 0.f, 0.f};
      floatx4 a1 = {0.f, 0.f, 0.f, 0.f};
#pragma unroll
      for (int t = 0; t < 5; ++t) {
        const ushort_t* pf = rowp[t] + (2 * tj) * 16 * CGP;
        const short4_t lo = *(const short4_t*)pf;
        const short4_t hh = *(const short4_t*)(pf + 4);
        const short8 bf = {lo[0], lo[1], lo[2], lo[3], hh[0], hh[1], hh[2], hh[3]};
        a0 = __builtin_amdgcn_mfma_f32_16x16x32_bf16(bf, aw[t], a0, 0, 0, 0);
      }
#pragma unroll
      for (int t = 0; t < 5; ++t) {
        const ushort_t* pf = rowp[t] + (2 * tj + 1) * 16 * CGP;
        const short4_t lo = *(const short4_t*)pf;
        const short4_t hh = *(const short4_t*)(pf + 4);
        const short8 bf = {lo[0], lo[1], lo[2], lo[3], hh[0], hh[1], hh[2], hh[3]};
        a1 = __builtin_amdgcn_mfma_f32_16x16x32_bf16(bf, aw[t], a1, 0, 0, 0);
      }
      // bias per acc's own oc (=pxl), BEFORE the permute
#pragma unroll
      for (int k = 0; k < 4; ++k) { a0[k] += bb; a1[k] += bb; }
      // register transpose via ds_bpermute: one nt dwordx4 per 8 oc-rows,
      // each instruction = 8 FULL 128-B lines.
      floatx4 v0, v1;
#pragma unroll
      for (int k = 0; k < 4; ++k) {
        const int p00 = __builtin_amdgcn_ds_bpermute(sl0, __float_as_int(a0[k]));
        const int p01 = __builtin_amdgcn_ds_bpermute(sl0, __float_as_int(a1[k]));
        v0[k] = __int_as_float(hi ? p01 : p00);
        const int p10 = __builtin_amdgcn_ds_bpermute(sl1, __float_as_int(a0[k]));
        const int p11 = __builtin_amdgcn_ds_bpermute(sl1, __float_as_int(a1[k]));
        v1[k] = __int_as_float(hi ? p11 : p10);
      }
      __builtin_nontemporal_store(v0, (floatx4*)(outr0 + tj * 32));
      __builtin_nontemporal_store(v1, (floatx4*)(outr1 + tj * 32));
    }
  };

  auto wrap6 = [](int v) { return v >= 6 ? v - 6 : v; };
  int m6 = (4 * q0 + 5) % 6;                 // slot of row rho = 4q-1 (ring-6)

  // ---- prologue: stage 6 rows ----
  {
    float ra[NP][4], rb[NP][4];
    LOADR(4 * q0 - 1, ra); LOADR(4 * q0 + 0, rb);
    CVTR(4 * q0 - 1, wrap6(m6 + 0), ra); CVTR(4 * q0 + 0, wrap6(m6 + 1), rb);
    LOADR(4 * q0 + 1, ra); LOADR(4 * q0 + 2, rb);
    CVTR(4 * q0 + 1, wrap6(m6 + 2), ra); CVTR(4 * q0 + 2, wrap6(m6 + 3), rb);
    LOADR(4 * q0 + 3, ra); LOADR(4 * q0 + 4, rb);
    CVTR(4 * q0 + 3, wrap6(m6 + 4), ra); CVTR(4 * q0 + 4, wrap6(m6 + 5), rb);
  }
  barrier_lgkm();

  // ---- task loop: straight-line body; final iteration peeled ----
#pragma unroll 1
  for (int q = q0; q < qend - 1; ++q) {
    float ra[NP][4], rb[NP][4], rc[NP][4], rd[NP][4];
    LOADR(4 * q + 5, ra); LOADR(4 * q + 6, rb);
    LOADR(4 * q + 7, rc); LOADR(4 * q + 8, rd);
    COMPUTE(q, m6);                          // prefetch drains under this
    barrier_lgkm();                          // tile readers done (lgkm only)
    CVTR(4 * q + 5, m6,            ra);
    CVTR(4 * q + 6, wrap6(m6 + 1), rb);
    CVTR(4 * q + 7, wrap6(m6 + 2), rc);
    CVTR(4 * q + 8, wrap6(m6 + 3), rd);
    barrier_lgkm();                          // tile ready for next task
    m6 = wrap6(m6 + 4);
  }
  COMPUTE(qend - 1, m6);                     // epilogue: no staging
}

extern "C" __global__ void __launch_bounds__(256, 3) conv_all(
    const float* __restrict__ x, const float* __restrict__ wgt,
    const float* __restrict__ bias, float* __restrict__ out) {
  extern __shared__ ushort_t lds[];
  // Balanced XCD map: xcd = bid&7 = batch; j = bid>>3 indexes the batch's 108
  // blocks ordered [G3(36) | G2(24) | G1(24) | G0(24)], each [wb][r][chunk].
  const int bid = blockIdx.x;
  const int b = bid & 7;
  const int j = bid >> 3;
  if (j < 36)      conv_group<3>(x, wgt, bias, out, lds, b, j);       // 2*18*1
  else if (j < 60) conv_group<2>(x, wgt, bias, out, lds, b, j - 36);  // 2*12*1
  else if (j < 84) conv_group<1>(x, wgt, bias, out, lds, b, j - 60);  // 2*6*2
  else             conv_group<0>(x, wgt, bias, out, lds, b, j - 84);  // 2*1*12
}

extern "C" void kernel_launch(void* const* d_in, const int* in_sizes, int n_in,
                              void* d_out, int out_size, void* d_ws, size_t ws_size,
                              hipStream_t stream) {
  const float* x    = (const float*)d_in[0];
  const float* wgt  = (const float*)d_in[1];
  const float* bias = (const float*)d_in[2];
  float* out        = (float*)d_out;

  // dynamic LDS (max over groups, G3): 6*196*20*2 + 5120 = 52160 B -> 3 blocks/CU
  const size_t lds_bytes = (size_t)(6 * 196 * CGP + 5 * 4 * 16 * 8) * 2;
  conv_all<<<dim3(864), dim3(256), lds_bytes, stream>>>(x, wgt, bias, out);
}